// Round 5
// baseline (686.526 us; speedup 1.0000x reference)
//
#include <hip/hip_runtime.h>

// ============================================================================
// InheritedFullyConnectedFlexiLayerSizeArchCore: hypernetwork (caseNN) +
// per-case 4-layer dynamic MLP with skip connection.
//
// Strategy:
//  - fp32 everywhere EXCEPT the 4 big batched GEMMs (bf16 MFMA, fp32 accum)
//    and their activation buffers. CDNA4 has no fp32 MFMA; bf16 is the only
//    path under ~770us (fp32 vector floor).
//  - gen_w: per-thread-column GEMM, 64 case-accumulators kept as float2[32]
//    so the fma lowers to v_pk_fma_f32 (2 MAC/instr, full fp32 precision).
//    Kernel sits at 32 FLOP/B (just above machine balance ~25); halving VALU
//    makes it cleanly HBM-bound (~45us for the 256MiB Ww read).
//  - w transposed once ([i][o] -> [o][i]) so MFMA A/B frags are k-contiguous
//    and global_load_lds (wave-uniform dest, lane*16) stays linear. The
//    transpose tile uses an XOR chunk-swizzle: the naive columnar gather is a
//    16-way bank conflict; chunk' = oc ^ ((il>>3)&7) restores full bank
//    spread (residual 2-way = free per m136).
//  - domain GEMM: m97 structure (128x128 tile, BK=32, 4 waves, 4x4
//    mfma_f32_16x16x32_bf16 per wave, gload_lds w16, 2-barrier K-loop,
//    XCD-swizzled blockIdx). __launch_bounds__(256,3): cap ~170 VGPR ->
//    guaranteed 3 blocks/CU (m97's natural usage is 164; (256,2) risked the
//    allocator drifting past 170 and dropping to 2). T2-swizzle deliberately
//    NOT applied: null on 2-barrier loops per the regime gate.
//  - Scratch: d_out (128 MiB, fully overwritten by the last GEMM) doubles as
//    scratch for buffers dead before that write (buf1, wnat). d_ws need is
//    ~97.3 MiB (wt + buf0 + bias/ht/xb, all read during the final GEMM).
// ============================================================================

typedef __bf16 bf16;
typedef __bf16 bf16x4 __attribute__((ext_vector_type(4)));
typedef __bf16 bf16x8 __attribute__((ext_vector_type(8)));
typedef float  f32x2  __attribute__((ext_vector_type(2)));
typedef float  f32x4  __attribute__((ext_vector_type(4)));
typedef unsigned short u16x8 __attribute__((ext_vector_type(8)));

#define AS1 __attribute__((address_space(1)))
#define AS3 __attribute__((address_space(3)))

__device__ __forceinline__ void gl2lds16(const void* g, void* l) {
  // 16B-wide async global->LDS. LDS dest is wave-uniform base; HW adds lane*16.
  __builtin_amdgcn_global_load_lds((const AS1 unsigned int*)g,
                                   (AS3 unsigned int*)l, 16, 0, 0);
}

__device__ __forceinline__ float silu_f(float v) {
  return v / (1.0f + __expf(-v));
}

// ---------------------------------------------------------------------------
// h_t[hh][c] = silu(o[c] @ Wc[:,hh] + bc[hh])   (transposed for scalar loads)
// ---------------------------------------------------------------------------
__global__ void k_hyper(const float* __restrict__ o, const float* __restrict__ Wc,
                        const float* __restrict__ bc, float* __restrict__ ht) {
  __shared__ float os[64];
  int c = blockIdx.x;       // 64 cases
  int j = threadIdx.x;      // 256 hidden units
  if (j < 64) os[j] = o[c * 64 + j];
  __syncthreads();
  float a = bc[j];
#pragma unroll
  for (int i = 0; i < 64; ++i) a = fmaf(os[i], Wc[i * 256 + j], a);
  ht[j * 64 + c] = silu_f(a);
}

// ---------------------------------------------------------------------------
// x -> bf16
// ---------------------------------------------------------------------------
__global__ void k_xcast(const float* __restrict__ x, bf16* __restrict__ xb) {
  int i = (blockIdx.x * 256 + threadIdx.x) * 4;
  float4 v = *(const float4*)(x + i);
  bf16x4 r = { (bf16)v.x, (bf16)v.y, (bf16)v.z, (bf16)v.w };
  *(bf16x4*)(xb + i) = r;
}

// ---------------------------------------------------------------------------
// wnat[(l*64+c)][d] = bf16( sum_hh ht[hh][c]*Ww[l][hh][d] + bw[l][d] )
// thread <-> one d (coalesced Ww reads); 64 fp32 case-accumulators held as
// float2[32] -> v_pk_fma_f32 (2 MAC/instr). h loads are thread-uniform ->
// s_load, SGPR broadcast operand.
// ---------------------------------------------------------------------------
__global__ __launch_bounds__(256, 4) void k_genw(const float* __restrict__ Ww,
                                                 const float* __restrict__ bw,
                                                 const float* __restrict__ ht,
                                                 bf16* __restrict__ wnat) {
  int l = blockIdx.x >> 8;                       // 4 layers x 256 d-tiles
  int d = (blockIdx.x & 255) * 256 + threadIdx.x;
  const float* wp = Ww + (size_t)l * 256 * 65536 + d;
  f32x2 acc[32];
#pragma unroll
  for (int c = 0; c < 32; ++c) acc[c] = (f32x2){0.f, 0.f};
  float wcur = wp[0];
  for (int hh = 0; hh < 256; ++hh) {
    float wnext = (hh < 255) ? wp[(size_t)(hh + 1) * 65536] : 0.f;
    const f32x2* hp = (const f32x2*)(ht + hh * 64);
    f32x2 wv = {wcur, wcur};
#pragma unroll
    for (int c = 0; c < 32; ++c) {
      f32x2 h2 = hp[c];
      acc[c].x = fmaf(h2.x, wv.x, acc[c].x);   // pairs lower to v_pk_fma_f32
      acc[c].y = fmaf(h2.y, wv.y, acc[c].y);
    }
    wcur = wnext;
  }
  float bv = bw[(size_t)l * 65536 + d];
#pragma unroll
  for (int c = 0; c < 32; ++c) {
    wnat[(size_t)(l * 64 + 2 * c) * 65536 + d]     = (bf16)(acc[c].x + bv);
    wnat[(size_t)(l * 64 + 2 * c + 1) * 65536 + d] = (bf16)(acc[c].y + bv);
  }
}

// ---------------------------------------------------------------------------
// bias[(l*64+c)][oo] = sum_hh ht[hh][c]*Wb[l][hh][oo] + bb[l][oo]
// One (l,c) per block; Wb slice (256KiB) is L2-hot across the 64 c-blocks.
// ---------------------------------------------------------------------------
__global__ void k_genb(const float* __restrict__ Wb, const float* __restrict__ bb,
                       const float* __restrict__ ht, float* __restrict__ bias) {
  int l = blockIdx.x >> 6;          // 4 layers x 64 cases
  int c = blockIdx.x & 63;
  int oo = threadIdx.x;
  const float* wp = Wb + (size_t)l * 65536 + oo;
  float acc = 0.f;
  for (int hh = 0; hh < 256; ++hh)
    acc = fmaf(ht[hh * 64 + c], wp[hh * 256], acc);
  bias[(size_t)(l * 64 + c) * 256 + oo] = acc + bb[l * 256 + oo];
}

// ---------------------------------------------------------------------------
// wt[(l*64+c)][o][i] = wnat[(l*64+c)][i][o]   (64x64 LDS-tiled transpose)
// Element (il, ol) stored at T[il][ ((ol>>3) ^ ((il>>3)&7))*8 + (ol&7) ].
//  - write: 16B chunks, chunk' = oc ^ ((il>>3)&7)  -> optimal b128 pattern
//  - read (columnar gather): cc survives into the bank index -> residual
//    2-way (pairs t,t+8) which is free. Was 16-way with naive pad.
// ---------------------------------------------------------------------------
__global__ void k_tw(const unsigned short* __restrict__ w,
                     unsigned short* __restrict__ wt) {
  __shared__ unsigned short T[64][64];
  int b = blockIdx.x;               // 256 (l,c) x 16 tiles
  int lc = b >> 4, tile = b & 15;
  int i0 = (tile >> 2) << 6, o0 = (tile & 3) << 6;
  const unsigned short* src = w + (size_t)lc * 65536;
  unsigned short* dst = wt + (size_t)lc * 65536;
  int t = threadIdx.x;
  for (int q = t; q < 512; q += 256) {
    int r = q >> 3, cc = q & 7;     // src row i0+r, o-chunk cc
    u16x8 v = *(const u16x8*)(src + (size_t)(i0 + r) * 256 + o0 + cc * 8);
    *(u16x8*)&T[r][(cc ^ ((r >> 3) & 7)) * 8] = v;
  }
  __syncthreads();
  for (int q = t; q < 512; q += 256) {
    int r = q >> 3, cc = q & 7;     // out row o0+r, i-chunk cc
    u16x8 v;
#pragma unroll
    for (int e = 0; e < 8; ++e) {
      int il = cc * 8 + e;
      v[e] = T[il][((((r >> 3) ^ (il >> 3)) & 7) << 3) + (r & 7)];
    }
    *(u16x8*)(dst + (size_t)(o0 + r) * 256 + i0 + cc * 8) = v;
  }
}

// ---------------------------------------------------------------------------
// Batched GEMM: Y[c] = epilogue( A[c][2048x256] @ W_t[c]^T + bias[c] )
//   A (bf16, row-major, k-contig), B from wt ([n][k], k-contig).
//   128x128 tile, BK=32, 4 waves (2x2), 4x4 mfma_f32_16x16x32_bf16 each.
// LAYER 0/1: silu -> bf16 out. LAYER 2: silu + skip(buf0) -> bf16 (in-place
// into buf0; every idx is written by exactly the thread that reads it; store
// depends on the load -> no hazard). LAYER 3: identity -> fp32 d_out.
// ---------------------------------------------------------------------------
template <int LAYER>
__global__ __launch_bounds__(256, 3) void k_gemm(
    const bf16* __restrict__ A_base, const bf16* __restrict__ WT,
    const float* __restrict__ BIAS, bf16* __restrict__ Yout,
    const bf16* __restrict__ Skip, float* __restrict__ Fout) {
  __shared__ bf16 As[128 * 32];
  __shared__ bf16 Bs[128 * 32];
  int bx = blockIdx.x;
  bx = (bx & 7) * 256 + (bx >> 3);      // XCD swizzle, 2048 % 8 == 0 bijective
  int c  = bx >> 5;                     // 64 cases
  int tl = bx & 31;                     // 16 m-tiles x 2 n-tiles
  int m0 = (tl & 15) << 7;
  int n0 = (tl >> 4) << 7;
  int tid = threadIdx.x;
  int lane = tid & 63, wid = tid >> 6;
  int wm = wid >> 1, wn = wid & 1;

  const bf16* Ab = (LAYER == 0) ? A_base : (A_base + (size_t)c * 2048 * 256);
  const bf16* Bb = WT + (size_t)c * 65536;

  f32x4 acc[4][4] = {};

  int qb = (wid << 7) + lane;           // this wave's first chunk (of 512)
  int q2 = qb + 64;
  char* lA0 = (char*)As + (wid << 11);  // wave-uniform LDS bases (wid*2048 B)
  char* lB0 = (char*)Bs + (wid << 11);

  for (int kk = 0; kk < 8; ++kk) {
    int k0 = kk * 32;
    // stage A[128x32] and B[128x32]: 512 16B chunks each; chunk q -> row q>>2,
    // 16B sub-chunk q&3. LDS dest is exactly linear (byte q*16).
    gl2lds16((const char*)(Ab + (size_t)(m0 + (qb >> 2)) * 256 + k0) + (qb & 3) * 16, lA0);
    gl2lds16((const char*)(Ab + (size_t)(m0 + (q2 >> 2)) * 256 + k0) + (q2 & 3) * 16, lA0 + 1024);
    gl2lds16((const char*)(Bb + (size_t)(n0 + (qb >> 2)) * 256 + k0) + (qb & 3) * 16, lB0);
    gl2lds16((const char*)(Bb + (size_t)(n0 + (q2 >> 2)) * 256 + k0) + (q2 & 3) * 16, lB0 + 1024);
    __syncthreads();

    bf16x8 af[4], bfr[4];
    int krow = (lane >> 4) * 8;
#pragma unroll
    for (int i = 0; i < 4; ++i) {
      af[i]  = *(const bf16x8*)&As[(wm * 64 + i * 16 + (lane & 15)) * 32 + krow];
      bfr[i] = *(const bf16x8*)&Bs[(wn * 64 + i * 16 + (lane & 15)) * 32 + krow];
    }
#pragma unroll
    for (int i = 0; i < 4; ++i)
#pragma unroll
      for (int j = 0; j < 4; ++j)
        acc[i][j] = __builtin_amdgcn_mfma_f32_16x16x32_bf16(af[i], bfr[j],
                                                            acc[i][j], 0, 0, 0);
    __syncthreads();
  }

  // epilogue: D row = (lane>>4)*4 + r, col = lane&15 (m89-verified mapping)
  const float* bp = BIAS + c * 256;
#pragma unroll
  for (int i = 0; i < 4; ++i) {
    int row = m0 + wm * 64 + i * 16 + (lane >> 4) * 4;
#pragma unroll
    for (int j = 0; j < 4; ++j) {
      int col = n0 + wn * 64 + j * 16 + (lane & 15);
      float bv = bp[col];
#pragma unroll
      for (int r = 0; r < 4; ++r) {
        float v = acc[i][j][r] + bv;
        size_t idx = ((size_t)c * 2048 + (row + r)) * 256 + col;
        if (LAYER < 3) {
          float s = silu_f(v);
          if (LAYER == 2) s += (float)Skip[idx];
          Yout[idx] = (bf16)s;
        } else {
          Fout[idx] = v;
        }
      }
    }
  }
}

// ---------------------------------------------------------------------------
extern "C" void kernel_launch(void* const* d_in, const int* in_sizes, int n_in,
                              void* d_out, int out_size, void* d_ws, size_t ws_size,
                              hipStream_t stream) {
  const float* x  = (const float*)d_in[0];
  const float* o  = (const float*)d_in[1];
  const float* Wc = (const float*)d_in[2];
  const float* bc = (const float*)d_in[3];
  const float* Ww = (const float*)d_in[4];
  const float* bw = (const float*)d_in[5];
  const float* Wb = (const float*)d_in[6];
  const float* bb = (const float*)d_in[7];
  float* out = (float*)d_out;
  char* ws = (char*)d_ws;

  // --- d_ws layout (everything here is read during the final GEMM) ---
  //   wt    [0,      32M)   bf16 [l*64+c][o*256+i]
  //   buf0  [32M,    96M)   bf16 activations (y0, later y2=y2+y0)
  //   bias  [96M,  +256K)   fp32 [l*64+c][256]
  //   ht    [..,   +64K )   fp32 [256][64]
  //   xb    [..,   +1M  )   bf16 x
  // --- d_out overlay (128 MiB; poisoned each call, fully rewritten by
  //     k_gemm<3>; only buffers DEAD before that write may live here) ---
  //   buf1  [0,      64M)   bf16 y1   (dead after k_gemm<2>)
  //   wnat  [64M,    96M)   bf16 natural-layout w (dead after k_tw)
  if (ws_size < 102039552ULL) return;  // need ~97.3 MiB scratch
  bf16*  wt   = (bf16*)(ws);
  bf16*  buf0 = (bf16*)(ws + 33554432);
  float* bias = (float*)(ws + 100663296);
  float* ht   = (float*)(ws + 100925440);
  bf16*  xb   = (bf16*)(ws + 100990976);
  bf16*  buf1 = (bf16*)(out);
  bf16*  wnat = (bf16*)((char*)out + 67108864);

  k_hyper<<<64, 256, 0, stream>>>(o, Wc, bc, ht);
  k_xcast<<<512, 256, 0, stream>>>(x, xb);
  k_genw<<<1024, 256, 0, stream>>>(Ww, bw, ht, wnat);
  k_genb<<<256, 256, 0, stream>>>(Wb, bb, ht, bias);
  k_tw<<<4096, 256, 0, stream>>>((const unsigned short*)wnat, (unsigned short*)wt);

  k_gemm<0><<<2048, 256, 0, stream>>>(xb,   wt,               bias,             buf0, nullptr, nullptr);
  k_gemm<1><<<2048, 256, 0, stream>>>(buf0, wt + 1 * 4194304, bias + 1 * 16384, buf1, nullptr, nullptr);
  k_gemm<2><<<2048, 256, 0, stream>>>(buf1, wt + 2 * 4194304, bias + 2 * 16384, buf0, buf0,    nullptr);
  k_gemm<3><<<2048, 256, 0, stream>>>(buf0, wt + 3 * 4194304, bias + 3 * 16384, nullptr, nullptr, out);
}

// Round 8
// 579.710 us; speedup vs baseline: 1.1843x; 1.1843x over previous
//
#include <hip/hip_runtime.h>

// ============================================================================
// InheritedFullyConnectedFlexiLayerSizeArchCore: hypernetwork (caseNN) +
// per-case 4-layer dynamic MLP with skip connection.
//
// R7 = R6 + LDS alignment fix (char arrays -> aligned(16); ds_read_b128 on
// 1-byte-aligned LDS is UB). Full desk re-audit of vmcnt ledger, fragment
// maps (identical to R4 HW-validated k_gemm), swizzle involutions.
//
//  - k_genw: MFMA-f16 GEMM (M=64 c, K=256 hh, N=65536 d per layer): h
//    broadcast via matrix pipe (VALU version was load-bound, 207us at
//    VALUBusy 30%). f16 keeps precision (11-bit mantissa >> bf16's 8).
//  - k_gemm: 3-slot pipeline, counted vmcnt(8/4/0) + raw s_barrier (T3/T4),
//    stage(k+2) before compute(k). Ledger: slot s=(k+2)%3 written at iter k;
//    last readers finished before BAR_B(k-1) < stage(k). Reads of slot k%3
//    gated by per-wave vmcnt + BAR_A (promotes to workgroup-wide).
//  - k_genb: 1024-thread blocks, hh split x4 + LDS reduce.
// ============================================================================

typedef __bf16 bf16;
typedef __bf16 bf16x4 __attribute__((ext_vector_type(4)));
typedef __bf16 bf16x8 __attribute__((ext_vector_type(8)));
typedef _Float16 f16;
typedef _Float16 f16x8 __attribute__((ext_vector_type(8)));
typedef float  f32x4  __attribute__((ext_vector_type(4)));
typedef unsigned short u16x8 __attribute__((ext_vector_type(8)));

#define AS1 __attribute__((address_space(1)))
#define AS3 __attribute__((address_space(3)))

__device__ __forceinline__ void gl2lds16(const void* g, void* l) {
  // 16B-wide async global->LDS. Global src addr is PER-LANE; LDS dest is
  // wave-uniform base + lane*16 (m104/m173).
  __builtin_amdgcn_global_load_lds((const AS1 unsigned int*)g,
                                   (AS3 unsigned int*)l, 16, 0, 0);
}

__device__ __forceinline__ float silu_f(float v) {
  return v / (1.0f + __expf(-v));
}

// ---------------------------------------------------------------------------
// ht[hh][c] (f32, for k_genb) and hb16[c][hh] (f16, A-operand for k_genw).
// ---------------------------------------------------------------------------
__global__ void k_hyper(const float* __restrict__ o, const float* __restrict__ Wc,
                        const float* __restrict__ bc, float* __restrict__ ht,
                        f16* __restrict__ hb16) {
  __shared__ float os[64];
  int c = blockIdx.x;       // 64 cases
  int j = threadIdx.x;      // 256 hidden units
  if (j < 64) os[j] = o[c * 64 + j];
  __syncthreads();
  float a = bc[j];
#pragma unroll
  for (int i = 0; i < 64; ++i) a = fmaf(os[i], Wc[i * 256 + j], a);
  float h = silu_f(a);
  ht[j * 64 + c] = h;
  hb16[c * 256 + j] = (f16)h;
}

// ---------------------------------------------------------------------------
// x -> bf16
// ---------------------------------------------------------------------------
__global__ void k_xcast(const float* __restrict__ x, bf16* __restrict__ xb) {
  int i = (blockIdx.x * 256 + threadIdx.x) * 4;
  float4 v = *(const float4*)(x + i);
  bf16x4 r = { (bf16)v.x, (bf16)v.y, (bf16)v.z, (bf16)v.w };
  *(bf16x4*)(xb + i) = r;
}

// ---------------------------------------------------------------------------
// k_genw: wnat[(l*64+c)][d] = bf16( sum_hh h[c][hh]*Ww[l][hh][d] + bw[l][d] )
// MFMA-f16. Block (512 thr, 8 waves) owns layer l, d-tile of 256, full K=256.
//  - h16 [64][256] f16 staged once in LDS, chunk-XOR-swizzled (g^(c&7)):
//    A-frag ds_read_b128 lands 2-way (free); unswizzled would be 16-way.
//  - Ww tiles [32 hh][256 d] f32 staged to 3 LDS slots via gl_lds w16
//    (1KB rows; 4 instr/wave/stage), counted vmcnt(8/4/0) pipeline.
//  - B-frag: 8 strided ds_read_b32 + cvt f32->f16 (4-way conflict, ~1.58x,
//    hidden under the 40.6us HBM floor for the 256MiB Ww read).
// ---------------------------------------------------------------------------
__global__ __launch_bounds__(512, 1) void k_genw(
    const float* __restrict__ Ww, const float* __restrict__ bw,
    const f16* __restrict__ hb16, bf16* __restrict__ wnat) {
  __shared__ __attribute__((aligned(16))) char Hs[32768];        // h16 [64][256] swz
  __shared__ __attribute__((aligned(16))) char Wslot[3][32768];  // Ww [32][256] f32
  int l = blockIdx.x >> 8;             // 4 layers x 256 d-tiles
  int d0 = (blockIdx.x & 255) * 256;
  const float* Wwl = Ww + (size_t)l * 16777216;
  int tid = threadIdx.x, lane = tid & 63, wid = tid >> 6;

  // stage h16 (2048 16B chunks; coalesced reads, swizzled ds_write)
  for (int q = tid; q < 2048; q += 512) {
    int c = q >> 5, g = q & 31;
    f16x8 v = *(const f16x8*)(hb16 + c * 256 + g * 8);
    *(f16x8*)(Hs + c * 512 + ((g ^ (c & 7)) << 4)) = v;
  }
  __syncthreads();   // also drains vmcnt(0) -> manual counts below are exact

  auto STAGE = [&](int s, int t) {
#pragma unroll
    for (int ii = 0; ii < 4; ++ii) {
      int row = wid * 4 + ii;          // 32 rows, 1KB each
      gl2lds16(Wwl + (size_t)(t * 32 + row) * 65536 + d0 + lane * 4,
               &Wslot[s][row * 1024]);
    }
  };

  f32x4 acc[4][2] = {};
  STAGE(0, 0);
  STAGE(1, 1);
#pragma unroll
  for (int kk = 0; kk < 8; ++kk) {
    if (kk < 6) STAGE((kk + 2) % 3, kk + 2);
    if (kk < 6)       asm volatile("s_waitcnt vmcnt(8)" ::: "memory");
    else if (kk == 6) asm volatile("s_waitcnt vmcnt(4)" ::: "memory");
    else              asm volatile("s_waitcnt vmcnt(0)" ::: "memory");
    __builtin_amdgcn_s_barrier();      // slot kk%3 landed for all waves
    __builtin_amdgcn_sched_barrier(0);

    f16x8 af[4];
    int kc = kk * 4 + (lane >> 4);     // 16B chunk index along hh
#pragma unroll
    for (int mf = 0; mf < 4; ++mf) {
      int c = mf * 16 + (lane & 15);
      af[mf] = *(const f16x8*)(Hs + c * 512 + ((kc ^ (c & 7)) << 4));
    }
    const float* Ws = (const float*)&Wslot[kk % 3][0];
    f16x8 bfrag[2];
#pragma unroll
    for (int nf = 0; nf < 2; ++nf) {
      int n = wid * 32 + nf * 16 + (lane & 15);
#pragma unroll
      for (int j = 0; j < 8; ++j)
        bfrag[nf][j] = (f16)Ws[((lane >> 4) * 8 + j) * 256 + n];
    }
    asm volatile("s_waitcnt lgkmcnt(0)" ::: "memory");
    __builtin_amdgcn_sched_barrier(0); // rule 18
    __builtin_amdgcn_s_barrier();      // all reads done; next stage may write
#pragma unroll
    for (int mf = 0; mf < 4; ++mf)
#pragma unroll
      for (int nf = 0; nf < 2; ++nf)
        acc[mf][nf] = __builtin_amdgcn_mfma_f32_16x16x32_f16(
            af[mf], bfrag[nf], acc[mf][nf], 0, 0, 0);
  }

  // epilogue: C row=(lane>>4)*4+r (c), col=lane&15 (d) — HW-confirmed map
#pragma unroll
  for (int nf = 0; nf < 2; ++nf) {
    int d = d0 + wid * 32 + nf * 16 + (lane & 15);
    float bv = bw[(size_t)l * 65536 + d];
#pragma unroll
    for (int mf = 0; mf < 4; ++mf) {
      int cb = mf * 16 + (lane >> 4) * 4;
#pragma unroll
      for (int r = 0; r < 4; ++r)
        wnat[(size_t)(l * 64 + cb + r) * 65536 + d] = (bf16)(acc[mf][nf][r] + bv);
    }
  }
}

// ---------------------------------------------------------------------------
// bias[(l*64+c)][oo] = sum_hh ht[hh][c]*Wb[l][hh][oo] + bb[l][oo]
// 1024 threads: hh split x4 (q=tid>>8), LDS reduce. 256 blocks.
// ---------------------------------------------------------------------------
__global__ void k_genb(const float* __restrict__ Wb, const float* __restrict__ bb,
                       const float* __restrict__ ht, float* __restrict__ bias) {
  __shared__ float red[4][256];
  int l = blockIdx.x >> 6;          // 4 layers x 64 cases
  int c = blockIdx.x & 63;
  int q = threadIdx.x >> 8;         // hh quarter
  int oo = threadIdx.x & 255;
  const float* wp = Wb + (size_t)l * 65536 + oo;
  float a = 0.f;
#pragma unroll 4
  for (int hh = q * 64; hh < q * 64 + 64; ++hh)
    a = fmaf(ht[hh * 64 + c], wp[hh * 256], a);
  red[q][oo] = a;
  __syncthreads();
  if (q == 0)
    bias[(size_t)(l * 64 + c) * 256 + oo] =
        red[0][oo] + red[1][oo] + red[2][oo] + red[3][oo] + bb[l * 256 + oo];
}

// ---------------------------------------------------------------------------
// wt[(l*64+c)][o][i] = wnat[(l*64+c)][i][o]   (64x64 LDS-tiled transpose)
// XOR chunk-swizzle: columnar gather was 16-way bank conflict; chunk' =
// oc ^ ((il>>3)&7) restores bank spread (residual 2-way = free per m136).
// HW-validated in the R4 bench (passed, absmax 0.0117).
// ---------------------------------------------------------------------------
__global__ void k_tw(const unsigned short* __restrict__ w,
                     unsigned short* __restrict__ wt) {
  __shared__ __attribute__((aligned(16))) unsigned short T[64][64];
  int b = blockIdx.x;               // 256 (l,c) x 16 tiles
  int lc = b >> 4, tile = b & 15;
  int i0 = (tile >> 2) << 6, o0 = (tile & 3) << 6;
  const unsigned short* src = w + (size_t)lc * 65536;
  unsigned short* dst = wt + (size_t)lc * 65536;
  int t = threadIdx.x;
  for (int q = t; q < 512; q += 256) {
    int r = q >> 3, cc = q & 7;     // src row i0+r, o-chunk cc
    u16x8 v = *(const u16x8*)(src + (size_t)(i0 + r) * 256 + o0 + cc * 8);
    *(u16x8*)&T[r][(cc ^ ((r >> 3) & 7)) * 8] = v;
  }
  __syncthreads();
  for (int q = t; q < 512; q += 256) {
    int r = q >> 3, cc = q & 7;     // out row o0+r, i-chunk cc
    u16x8 v;
#pragma unroll
    for (int e = 0; e < 8; ++e) {
      int il = cc * 8 + e;
      v[e] = T[il][((((r >> 3) ^ (il >> 3)) & 7) << 3) + (r & 7)];
    }
    *(u16x8*)(dst + (size_t)(o0 + r) * 256 + i0 + cc * 8) = v;
  }
}

// ---------------------------------------------------------------------------
// Batched GEMM: Y[c] = epilogue( A[c][2048x256] @ W_t[c]^T + bias[c] )
//   128x128 tile, BK=32, 4 waves (2x2), 4x4 mfma_f32_16x16x32_bf16 each.
// 3-slot LDS pipeline (T3/T4): stage(k+2) at top of iter k; counted vmcnt
// (FIFO retire => oldest tile landed) + raw s_barrier; ds_read;
// lgkmcnt(0)+sched_barrier (rule 18); BAR_B; MFMA.
// LAYER 0/1: silu -> bf16. LAYER 2: silu + skip (in-place, self-element).
// LAYER 3: identity -> fp32 d_out.
// ---------------------------------------------------------------------------
template <int LAYER>
__global__ __launch_bounds__(256, 3) void k_gemm(
    const bf16* __restrict__ A_base, const bf16* __restrict__ WT,
    const float* __restrict__ BIAS, bf16* __restrict__ Yout,
    const bf16* __restrict__ Skip, float* __restrict__ Fout) {
  __shared__ __attribute__((aligned(16))) bf16 As[3][128 * 32];
  __shared__ __attribute__((aligned(16))) bf16 Bs[3][128 * 32];
  int bx = blockIdx.x;
  bx = (bx & 7) * 256 + (bx >> 3);      // XCD swizzle, 2048 % 8 == 0 bijective
  int c  = bx >> 5;                     // 64 cases
  int tl = bx & 31;                     // 16 m-tiles x 2 n-tiles
  int m0 = (tl & 15) << 7;
  int n0 = (tl >> 4) << 7;
  int tid = threadIdx.x;
  int lane = tid & 63, wid = tid >> 6;
  int wm = wid >> 1, wn = wid & 1;

  const bf16* Ab = (LAYER == 0) ? A_base : (A_base + (size_t)c * 2048 * 256);
  const bf16* Bb = WT + (size_t)c * 65536;

  int qb = (wid << 7) + lane;           // this wave's first chunk (of 512)
  int q2 = qb + 64;

  auto STAGE = [&](int slot, int t) {
    int k0 = t * 32;
    char* lA = (char*)&As[slot][0] + (wid << 11);   // wave-uniform LDS bases
    char* lB = (char*)&Bs[slot][0] + (wid << 11);
    gl2lds16((const char*)(Ab + (size_t)(m0 + (qb >> 2)) * 256 + k0) + (qb & 3) * 16, lA);
    gl2lds16((const char*)(Ab + (size_t)(m0 + (q2 >> 2)) * 256 + k0) + (q2 & 3) * 16, lA + 1024);
    gl2lds16((const char*)(Bb + (size_t)(n0 + (qb >> 2)) * 256 + k0) + (qb & 3) * 16, lB);
    gl2lds16((const char*)(Bb + (size_t)(n0 + (q2 >> 2)) * 256 + k0) + (q2 & 3) * 16, lB + 1024);
  };

  f32x4 acc[4][4] = {};
  STAGE(0, 0);
  STAGE(1, 1);
#pragma unroll
  for (int kk = 0; kk < 8; ++kk) {
    if (kk < 6) STAGE((kk + 2) % 3, kk + 2);
    if (kk < 6)       asm volatile("s_waitcnt vmcnt(8)" ::: "memory");
    else if (kk == 6) asm volatile("s_waitcnt vmcnt(4)" ::: "memory");
    else              asm volatile("s_waitcnt vmcnt(0)" ::: "memory");
    __builtin_amdgcn_s_barrier();       // BAR_A: all waves' slot kk%3 landed
    __builtin_amdgcn_sched_barrier(0);

    const bf16* Asl = &As[kk % 3][0];
    const bf16* Bsl = &Bs[kk % 3][0];
    bf16x8 af[4], bfr[4];
    int krow = (lane >> 4) * 8;
#pragma unroll
    for (int i = 0; i < 4; ++i) {
      af[i]  = *(const bf16x8*)&Asl[(wm * 64 + i * 16 + (lane & 15)) * 32 + krow];
      bfr[i] = *(const bf16x8*)&Bsl[(wn * 64 + i * 16 + (lane & 15)) * 32 + krow];
    }
    asm volatile("s_waitcnt lgkmcnt(0)" ::: "memory");
    __builtin_amdgcn_sched_barrier(0);  // rule 18: pin reads before BAR_B
    __builtin_amdgcn_s_barrier();       // BAR_B: reads done; stage may overwrite
#pragma unroll
    for (int i = 0; i < 4; ++i)
#pragma unroll
      for (int j = 0; j < 4; ++j)
        acc[i][j] = __builtin_amdgcn_mfma_f32_16x16x32_bf16(af[i], bfr[j],
                                                            acc[i][j], 0, 0, 0);
  }

  // epilogue: D row = (lane>>4)*4 + r, col = lane&15 (m89-verified mapping)
  const float* bp = BIAS + c * 256;
#pragma unroll
  for (int i = 0; i < 4; ++i) {
    int row = m0 + wm * 64 + i * 16 + (lane >> 4) * 4;
#pragma unroll
    for (int j = 0; j < 4; ++j) {
      int col = n0 + wn * 64 + j * 16 + (lane & 15);
      float bv = bp[col];
#pragma unroll
      for (int r = 0; r < 4; ++r) {
        float v = acc[i][j][r] + bv;
        size_t idx = ((size_t)c * 2048 + (row + r)) * 256 + col;
        if (LAYER < 3) {
          float s = silu_f(v);
          if (LAYER == 2) s += (float)Skip[idx];
          Yout[idx] = (bf16)s;
        } else {
          Fout[idx] = v;
        }
      }
    }
  }
}

// ---------------------------------------------------------------------------
extern "C" void kernel_launch(void* const* d_in, const int* in_sizes, int n_in,
                              void* d_out, int out_size, void* d_ws, size_t ws_size,
                              hipStream_t stream) {
  const float* x  = (const float*)d_in[0];
  const float* o  = (const float*)d_in[1];
  const float* Wc = (const float*)d_in[2];
  const float* bc = (const float*)d_in[3];
  const float* Ww = (const float*)d_in[4];
  const float* bw = (const float*)d_in[5];
  const float* Wb = (const float*)d_in[6];
  const float* bb = (const float*)d_in[7];
  float* out = (float*)d_out;
  char* ws = (char*)d_ws;

  // --- d_ws layout (everything here is read during the final GEMM) ---
  //   wt    [0,      32M)   bf16 [l*64+c][o*256+i]
  //   buf0  [32M,    96M)   bf16 activations (y0, later y2=y2+y0)
  //   bias  [96M,  +256K)   fp32 [l*64+c][256]
  //   ht    [..,   +64K )   fp32 [256][64]
  //   xb    [..,   +1M  )   bf16 x
  //   hb16  [..,   +32K )   f16  h [64 c][256 hh]
  // --- d_out overlay (128 MiB; poisoned each call, fully rewritten by
  //     k_gemm<3>; only buffers DEAD before that write may live here) ---
  //   buf1  [0,      64M)   bf16 y1        (dead after k_gemm<2>)
  //   wnat  [64M,    96M)   bf16 natural-w (dead after k_tw)
  if (ws_size < 102072320ULL) return;  // need ~97.4 MiB scratch
  bf16*  wt   = (bf16*)(ws);
  bf16*  buf0 = (bf16*)(ws + 33554432);
  float* bias = (float*)(ws + 100663296);
  float* ht   = (float*)(ws + 100925440);
  bf16*  xb   = (bf16*)(ws + 100990976);
  f16*   hb16 = (f16*)(ws + 102039552);
  bf16*  buf1 = (bf16*)(out);
  bf16*  wnat = (bf16*)((char*)out + 67108864);

  k_hyper<<<64, 256, 0, stream>>>(o, Wc, bc, ht, hb16);
  k_xcast<<<512, 256, 0, stream>>>(x, xb);
  k_genw<<<1024, 512, 0, stream>>>(Ww, bw, hb16, wnat);
  k_genb<<<256, 1024, 0, stream>>>(Wb, bb, ht, bias);
  k_tw<<<4096, 256, 0, stream>>>((const unsigned short*)wnat, (unsigned short*)wt);

  k_gemm<0><<<2048, 256, 0, stream>>>(xb,   wt,               bias,             buf0, nullptr, nullptr);
  k_gemm<1><<<2048, 256, 0, stream>>>(buf0, wt + 1 * 4194304, bias + 1 * 16384, buf1, nullptr, nullptr);
  k_gemm<2><<<2048, 256, 0, stream>>>(buf1, wt + 2 * 4194304, bias + 2 * 16384, buf0, buf0,    nullptr);
  k_gemm<3><<<2048, 256, 0, stream>>>(buf0, wt + 3 * 4194304, bias + 3 * 16384, nullptr, nullptr, out);
}